// Round 6
// baseline (172.135 us; speedup 1.0000x reference)
//
#include <hip/hip_runtime.h>
#include <hip/hip_bf16.h>
#include <hip/hip_cooperative_groups.h>

namespace cg = cooperative_groups;

#define TEMP_INV (1.0f / 0.07f)
#define EPS 1e-12f
// (1/0.07) * log2(e): exp(sim/T) == exp2(sim * C_EXP)
#define C_EXP 20.609929155556625f
#define NUM_CLASSES 16

#define BM 256          // rows per denom rowblock
#define BN 128          // cols per chunk
#define KD 128          // feature dim
#define NCHUNK 8        // col chunks per colgroup (1024 cols)
#define NPART 16        // denom partials per row = colgroups(8) * wc(2)

typedef __attribute__((ext_vector_type(4))) float f32x4;
typedef __attribute__((ext_vector_type(8))) short bf16x8;

__device__ __forceinline__ float bf2f(ushort u) {
    unsigned int x = ((unsigned int)u) << 16;
    return __uint_as_float(x);
}

// Swizzled LDS fragment address: element (r, slot) of a [rows][128] bf16 tile,
// slot = 16B chunk within the 256B row. Swizzle: slot ^= (r&7).
__device__ __forceinline__ const bf16x8* lds_frag(const ushort* base, int r, int slot) {
    int sw = slot ^ (r & 7);
    return reinterpret_cast<const bf16x8*>(
        reinterpret_cast<const char*>(base) + r * 256 + sw * 16);
}

// One cooperative kernel: normalize+classpart -> classreduce -> denom ->
// rowloss -> mean. 256 blocks x 512 threads, 128KB LDS => 1 block/CU.
__global__ __launch_bounds__(512) void supcon_all(
    const float* __restrict__ feat,
    const int* __restrict__ labels,
    ushort* __restrict__ fb,
    float* __restrict__ sq,
    float* __restrict__ g_part,     // [256][16][128]
    float* __restrict__ cnt_part,   // [256][16]
    float* __restrict__ g,          // [16][128]
    float* __restrict__ cntf,       // [16]
    float* __restrict__ denom_part, // [N][16]
    float* __restrict__ block_loss, // [256]
    float* __restrict__ out,
    int N) {

    cg::grid_group gridg = cg::this_grid();
    __shared__ __align__(16) char smem[131072];

    const int tid  = threadIdx.x;
    const int lane = tid & 63;
    const int wv   = tid >> 6;         // 0..7
    const int bx   = blockIdx.x;       // 0..255

    // ================= Phase 1: normalize + per-block class partials =======
    {
        float* lg = (float*)smem;              // [8][16][128] = 64KB
        float* lc = (float*)(smem + 65536);    // [8][16]
        for (int i = lane; i < NUM_CLASSES * 128; i += 64) lg[wv * 2048 + i] = 0.f;
        if (lane < NUM_CLASSES) lc[wv * 16 + lane] = 0.f;
        // each wave touches only its own region: no sync needed before use

        const int r0 = bx * 32 + wv * 4;
        for (int rr = 0; rr < 4; rr++) {
            const int r = r0 + rr;
            const float2 v = *reinterpret_cast<const float2*>(feat + (size_t)r * KD + lane * 2);
            float s = v.x * v.x + v.y * v.y;
            #pragma unroll
            for (int off = 1; off < 64; off <<= 1) s += __shfl_xor(s, off);
            const float scale = 1.0f / fmaxf(sqrtf(s), EPS);

            __hip_bfloat16 h0 = __float2bfloat16(v.x * scale);
            __hip_bfloat16 h1 = __float2bfloat16(v.y * scale);
            ushort u0 = *reinterpret_cast<ushort*>(&h0);
            ushort u1 = *reinterpret_cast<ushort*>(&h1);
            float q0 = bf2f(u0), q1 = bf2f(u1);
            float q = q0 * q0 + q1 * q1;
            #pragma unroll
            for (int off = 1; off < 64; off <<= 1) q += __shfl_xor(q, off);
            if (lane == 0) sq[r] = q;

            unsigned int pack = (unsigned int)u0 | ((unsigned int)u1 << 16);
            *reinterpret_cast<unsigned int*>(fb + (size_t)r * KD + lane * 2) = pack;

            const int lab = labels[r];          // wave-uniform
            lg[wv * 2048 + lab * 128 + lane * 2]     += q0;
            lg[wv * 2048 + lab * 128 + lane * 2 + 1] += q1;
            if (lane == 0) lc[wv * 16 + lab] += 1.f;
        }
        __syncthreads();
        for (int i = tid; i < NUM_CLASSES * 128; i += 512) {
            float acc = 0.f;
            #pragma unroll
            for (int w8 = 0; w8 < 8; w8++) acc += lg[w8 * 2048 + i];
            g_part[(size_t)bx * 2048 + i] = acc;
        }
        if (tid < NUM_CLASSES) {
            float acc = 0.f;
            #pragma unroll
            for (int w8 = 0; w8 < 8; w8++) acc += lc[w8 * 16 + tid];
            cnt_part[bx * NUM_CLASSES + tid] = acc;
        }
    }
    gridg.sync();

    // ================= Phase 2: class reduce (blocks 0..15) ================
    if (bx < NUM_CLASSES) {
        const int c = bx;
        float* lr  = (float*)smem;             // [4][128]
        float* lr2 = (float*)(smem + 2048);    // [4]
        const int d = tid & 127, seg = tid >> 7;   // seg 0..3
        float acc = 0.f;
        for (int b = seg * 64; b < seg * 64 + 64; b++)
            acc += g_part[(size_t)b * 2048 + c * 128 + d];
        lr[seg * 128 + d] = acc;

        float cv = 0.f;
        if (tid < 256) cv = cnt_part[tid * NUM_CLASSES + c];
        #pragma unroll
        for (int off = 1; off < 64; off <<= 1) cv += __shfl_xor(cv, off);
        if (tid < 256 && lane == 0) lr2[wv] = cv;
        __syncthreads();
        if (tid < 128) g[c * 128 + tid] = lr[tid] + lr[128 + tid] + lr[256 + tid] + lr[384 + tid];
        if (tid == 0)  cntf[c] = lr2[0] + lr2[1] + lr2[2] + lr2[3];
    }
    gridg.sync();

    // ================= Phase 3: denom partials (LDS-staged MFMA) ===========
    {
        ushort* As = (ushort*)smem;                   // 256x128 bf16, 64KB
        ushort* Bs0 = (ushort*)(smem + 65536);        // 128x128 bf16, 32KB
        ushort* Bs1 = (ushort*)(smem + 65536 + 32768);

        const int w    = wv;
        const int wr   = w >> 1;          // 0..3 (row quadrant)
        const int wc   = w & 1;           // 0..1 (col half)
        const int r16  = lane & 15;
        const int g4   = lane >> 4;

        const int rowblock = bx >> 3;     // 0..31
        const int colgroup = bx & 7;      // 0..7
        const int rowbase  = rowblock * BM;
        const int col0     = colgroup * (BN * NCHUNK);

        {
            const ushort* gA = fb + (size_t)rowbase * KD;
            #pragma unroll
            for (int i = 0; i < 8; i++) {
                int c = i * 512 + tid;
                bf16x8 v = *reinterpret_cast<const bf16x8*>(gA + c * 8);
                int dst = c ^ ((c >> 4) & 7);
                *reinterpret_cast<bf16x8*>(&As[dst * 8]) = v;
            }
            const ushort* gB = fb + (size_t)col0 * KD;
            #pragma unroll
            for (int i = 0; i < 4; i++) {
                int c = i * 512 + tid;
                bf16x8 v = *reinterpret_cast<const bf16x8*>(gB + c * 8);
                int dst = c ^ ((c >> 4) & 7);
                *reinterpret_cast<bf16x8*>(&Bs0[dst * 8]) = v;
            }
        }
        __syncthreads();

        float pd[4][4];
        #pragma unroll
        for (int m = 0; m < 4; m++)
            #pragma unroll
            for (int i = 0; i < 4; i++) pd[m][i] = 0.f;

        int cur = 0;
        for (int c = 0; c < NCHUNK; c++) {
            bf16x8 pre0, pre1, pre2, pre3;
            if (c + 1 < NCHUNK) {
                const ushort* gB = fb + (size_t)(col0 + (c + 1) * BN) * KD;
                pre0 = *reinterpret_cast<const bf16x8*>(gB + (0 * 512 + tid) * 8);
                pre1 = *reinterpret_cast<const bf16x8*>(gB + (1 * 512 + tid) * 8);
                pre2 = *reinterpret_cast<const bf16x8*>(gB + (2 * 512 + tid) * 8);
                pre3 = *reinterpret_cast<const bf16x8*>(gB + (3 * 512 + tid) * 8);
            }

            f32x4 acc[4][4];
            #pragma unroll
            for (int m = 0; m < 4; m++)
                #pragma unroll
                for (int n = 0; n < 4; n++) acc[m][n] = f32x4{0.f, 0.f, 0.f, 0.f};

            const ushort* bbase = cur ? Bs1 : Bs0;
            #pragma unroll
            for (int ks = 0; ks < 4; ks++) {
                const int slot = ks * 4 + g4;
                bf16x8 av[4], bv[4];
                #pragma unroll
                for (int m = 0; m < 4; m++)
                    av[m] = *lds_frag(As, wr * 64 + m * 16 + r16, slot);
                #pragma unroll
                for (int n = 0; n < 4; n++)
                    bv[n] = *lds_frag(bbase, wc * 64 + n * 16 + r16, slot);
                #pragma unroll
                for (int m = 0; m < 4; m++)
                    #pragma unroll
                    for (int n = 0; n < 4; n++)
                        acc[m][n] = __builtin_amdgcn_mfma_f32_16x16x32_bf16(av[m], bv[n], acc[m][n], 0, 0, 0);
            }

            #pragma unroll
            for (int m = 0; m < 4; m++)
                #pragma unroll
                for (int n = 0; n < 4; n++)
                    #pragma unroll
                    for (int i = 0; i < 4; i++)
                        pd[m][i] += __builtin_amdgcn_exp2f(acc[m][n][i] * C_EXP);

            if (c + 1 < NCHUNK) {
                ushort* dstb = cur ? Bs0 : Bs1;
                int ch;
                ch = 0 * 512 + tid; *reinterpret_cast<bf16x8*>(&dstb[(ch ^ ((ch >> 4) & 7)) * 8]) = pre0;
                ch = 1 * 512 + tid; *reinterpret_cast<bf16x8*>(&dstb[(ch ^ ((ch >> 4) & 7)) * 8]) = pre1;
                ch = 2 * 512 + tid; *reinterpret_cast<bf16x8*>(&dstb[(ch ^ ((ch >> 4) & 7)) * 8]) = pre2;
                ch = 3 * 512 + tid; *reinterpret_cast<bf16x8*>(&dstb[(ch ^ ((ch >> 4) & 7)) * 8]) = pre3;
            }
            __syncthreads();
            cur ^= 1;
        }

        #pragma unroll
        for (int off = 1; off < 16; off <<= 1)
            #pragma unroll
            for (int m = 0; m < 4; m++)
                #pragma unroll
                for (int i = 0; i < 4; i++)
                    pd[m][i] += __shfl_xor(pd[m][i], off);

        if (r16 == 0) {
            const int part = colgroup * 2 + wc;   // 0..15
            #pragma unroll
            for (int m = 0; m < 4; m++)
                #pragma unroll
                for (int i = 0; i < 4; i++) {
                    int r = rowbase + wr * 64 + m * 16 + g4 * 4 + i;
                    denom_part[(size_t)r * NPART + part] = pd[m][i];
                }
        }
    }
    gridg.sync();

    // ================= Phase 4: rowloss + per-block sum ====================
    {
        float* lsum = (float*)smem;   // [8]
        const int r0 = bx * 32 + wv * 4;
        float wloss = 0.f;
        for (int rr = 0; rr < 4; rr++) {
            const int r = r0 + rr;
            const int lab = labels[r];
            unsigned int pk = *reinterpret_cast<const unsigned int*>(fb + (size_t)r * KD + lane * 2);
            float f0 = bf2f((ushort)(pk & 0xffff));
            float f1 = bf2f((ushort)(pk >> 16));
            const float2 gv = *reinterpret_cast<const float2*>(g + lab * 128 + lane * 2);
            float p = f0 * gv.x + f1 * gv.y;
            #pragma unroll
            for (int off = 1; off < 64; off <<= 1) p += __shfl_xor(p, off);

            float dsum = (lane < NPART) ? denom_part[(size_t)r * NPART + lane] : 0.f;
            #pragma unroll
            for (int off = 1; off < NPART; off <<= 1) dsum += __shfl_xor(dsum, off);

            if (lane == 0) {
                float sqr    = sq[r];
                float possum = (p - sqr) * TEMP_INV;
                float cnt    = cntf[lab] - 1.0f;
                float dn     = dsum - __builtin_amdgcn_exp2f(sqr * C_EXP);
                wloss += -(possum - cnt * logf(dn + EPS)) / (cnt + EPS);
            }
        }
        if (lane == 0) lsum[wv] = wloss;
        __syncthreads();
        if (tid == 0) {
            float t = 0.f;
            #pragma unroll
            for (int i = 0; i < 8; i++) t += lsum[i];
            block_loss[bx] = t;
        }
    }
    gridg.sync();

    // ================= Phase 5: final mean (block 0) =======================
    if (bx == 0) {
        float* lr = (float*)smem;
        float s = (tid < 256) ? block_loss[tid] : 0.f;
        #pragma unroll
        for (int off = 1; off < 64; off <<= 1) s += __shfl_xor(s, off);
        if (lane == 0) lr[wv] = s;
        __syncthreads();
        if (tid == 0) {
            float t = 0.f;
            #pragma unroll
            for (int i = 0; i < 8; i++) t += lr[i];
            out[0] = t / (float)N;
        }
    }
}

extern "C" void kernel_launch(void* const* d_in, const int* in_sizes, int n_in,
                              void* d_out, int out_size, void* d_ws, size_t ws_size,
                              hipStream_t stream) {
    const float* feat = (const float*)d_in[0];
    const int* labels = (const int*)d_in[1];
    int N = in_sizes[1];
    const int D = in_sizes[0] / N;
    (void)D;

    char* ws = (char*)d_ws;
    size_t off = 0;
    ushort* fb        = (ushort*)(ws + off); off += (size_t)N * KD * sizeof(ushort);
    float* sq         = (float*)(ws + off);  off += (size_t)N * sizeof(float);
    float* g_part     = (float*)(ws + off);  off += (size_t)256 * NUM_CLASSES * KD * sizeof(float);
    float* cnt_part   = (float*)(ws + off);  off += (size_t)256 * NUM_CLASSES * sizeof(float);
    float* g          = (float*)(ws + off);  off += (size_t)NUM_CLASSES * KD * sizeof(float);
    float* cntf       = (float*)(ws + off);  off += (size_t)NUM_CLASSES * sizeof(float);
    float* denom_part = (float*)(ws + off);  off += (size_t)N * NPART * sizeof(float);
    float* block_loss = (float*)(ws + off);  off += (size_t)256 * sizeof(float);
    float* outp       = (float*)d_out;

    void* args[] = {
        (void*)&feat, (void*)&labels, (void*)&fb, (void*)&sq,
        (void*)&g_part, (void*)&cnt_part, (void*)&g, (void*)&cntf,
        (void*)&denom_part, (void*)&block_loss, (void*)&outp, (void*)&N
    };
    hipLaunchCooperativeKernel((const void*)supcon_all,
                               dim3(N / 32), dim3(512), args, 0, stream);
}

// Round 7
// 62.611 us; speedup vs baseline: 2.7493x; 2.7493x over previous
//
#include <hip/hip_runtime.h>
#include <hip/hip_bf16.h>

#define TEMP_INV (1.0f / 0.07f)
#define EPS 1e-12f
// (1/0.07) * log2(e): exp(sim/T) == exp2(sim * C_EXP)
#define C_EXP 20.609929155556625f
#define NUM_CLASSES 16
#define CS_BLOCKS 128

#define BM 128          // rows per denom block
#define BN 64           // cols per chunk
#define KD 128          // feature dim
#define NCHUNK 16       // col chunks per colgroup (1024 cols)
#define NPART 16        // denom partials per row = colgroups(8) * wc(2)

typedef __attribute__((ext_vector_type(4))) float f32x4;
typedef __attribute__((ext_vector_type(8))) short bf16x8;

__device__ __forceinline__ float bf2f(ushort u) {
    unsigned int x = ((unsigned int)u) << 16;
    return __uint_as_float(x);
}

// Swizzled LDS fragment address: element (r, slot) of a [rows][128] bf16 tile,
// slot = 16B chunk within the 256B row. Swizzle: slot ^= (r&7).
__device__ __forceinline__ const bf16x8* lds_frag(const ushort* base, int r, int slot) {
    int sw = slot ^ (r & 7);
    return reinterpret_cast<const bf16x8*>(
        reinterpret_cast<const char*>(base) + r * 256 + sw * 16);
}

// ---------------- Kernel A: L2-normalize rows -> bf16, emit ||f_bf16||^2 ----
// One wave per row; D=128 = 64 lanes x float2.
__global__ void normalize_kernel(const float* __restrict__ feat,
                                 ushort* __restrict__ fb,
                                 float* __restrict__ sq,
                                 int N) {
    int r    = (blockIdx.x * blockDim.x + threadIdx.x) >> 6;
    int lane = threadIdx.x & 63;
    if (r >= N) return;
    const float2 v = *reinterpret_cast<const float2*>(feat + (size_t)r * KD + lane * 2);
    float s = v.x * v.x + v.y * v.y;
    #pragma unroll
    for (int off = 1; off < 64; off <<= 1) s += __shfl_xor(s, off);
    const float scale = 1.0f / fmaxf(sqrtf(s), EPS);

    __hip_bfloat16 h0 = __float2bfloat16(v.x * scale);
    __hip_bfloat16 h1 = __float2bfloat16(v.y * scale);
    ushort u0 = *reinterpret_cast<ushort*>(&h0);
    ushort u1 = *reinterpret_cast<ushort*>(&h1);
    unsigned int pack = (unsigned int)u0 | ((unsigned int)u1 << 16);
    *reinterpret_cast<unsigned int*>(fb + (size_t)r * KD + lane * 2) = pack;

    float q0 = bf2f(u0), q1 = bf2f(u1);
    float q = q0 * q0 + q1 * q1;
    #pragma unroll
    for (int off = 1; off < 64; off <<= 1) q += __shfl_xor(q, off);
    if (lane == 0) sq[r] = q;
}

// ---------------- Kernel A2: per-class partial sums (no atomics, no memset) -
// 128 blocks x 64 rows; each thread owns LDS slot [half][class][col].
// Writes unconditional partials g_part[bx][16][128], cnt_part[bx][16].
__global__ __launch_bounds__(256) void classsum_kernel(
    const ushort* __restrict__ fb,
    const int* __restrict__ labels,
    float* __restrict__ g_part,
    float* __restrict__ cnt_part,
    int N) {
    __shared__ float lds[2][NUM_CLASSES][128];
    __shared__ float ldc[2][NUM_CLASSES];
    const int d    = threadIdx.x & 127;
    const int half = threadIdx.x >> 7;
    #pragma unroll
    for (int c = 0; c < NUM_CLASSES; c++) lds[half][c][d] = 0.f;
    if (d < NUM_CLASSES) ldc[half][d] = 0.f;
    __syncthreads();

    const int r0 = blockIdx.x * 64 + half * 32;
    for (int r = r0; r < r0 + 32; r++) {
        int lab = labels[r];
        lds[half][lab][d] += bf2f(fb[(size_t)r * KD + d]);
        if (d == 0) ldc[half][lab] += 1.f;
    }
    __syncthreads();

    for (int c = half; c < NUM_CLASSES; c += 2)
        g_part[(size_t)blockIdx.x * 2048 + c * 128 + d] = lds[0][c][d] + lds[1][c][d];
    if (threadIdx.x < NUM_CLASSES)
        cnt_part[blockIdx.x * NUM_CLASSES + threadIdx.x] =
            ldc[0][threadIdx.x] + ldc[1][threadIdx.x];
}

// ---------------- Kernel A3: reduce class partials --------------------------
// 16 blocks (one per class) x 128 threads.
__global__ void classreduce_kernel(const float* __restrict__ g_part,
                                   const float* __restrict__ cnt_part,
                                   float* __restrict__ g,
                                   float* __restrict__ cntf) {
    const int c = blockIdx.x;
    const int d = threadIdx.x;          // 0..127
    float acc = 0.f;
    for (int b = 0; b < CS_BLOCKS; b++)
        acc += g_part[(size_t)b * 2048 + c * 128 + d];
    g[c * 128 + d] = acc;

    __shared__ float sc[2];
    float cv = cnt_part[d * NUM_CLASSES + c];
    #pragma unroll
    for (int off = 1; off < 64; off <<= 1) cv += __shfl_xor(cv, off);
    if ((d & 63) == 0) sc[d >> 6] = cv;
    __syncthreads();
    if (d == 0) cntf[c] = sc[0] + sc[1];
}

// ---------------- Kernel B: denom partials via LDS-staged MFMA --------------
// 512 blocks (grid 8 colgroups x 64 rowblocks), 512 threads = 8 waves (4x2),
// wave tile 32x32. LDS = A(32KB) + B dbuf(2x16KB) = 64KB => 2 blocks/CU,
// 4 waves/SIMD. Each (colgroup, wc) writes denom_part[r*16 + part].
__global__ __launch_bounds__(512) void supcon_denom(
    const ushort* __restrict__ fb,
    float* __restrict__ denom_part,
    int N) {

    __shared__ __align__(16) ushort As[BM * KD];        // 32 KB
    __shared__ __align__(16) ushort Bs[2][BN * KD];     // 2 x 16 KB

    const int tid  = threadIdx.x;
    const int lane = tid & 63;
    const int w    = tid >> 6;        // 0..7
    const int wr   = w >> 1;          // 0..3 (32-row band)
    const int wc   = w & 1;           // 0..1 (32-col half)
    const int r16  = lane & 15;
    const int g4   = lane >> 4;       // 0..3

    const int rowbase = blockIdx.y * BM;
    const int col0    = blockIdx.x * (BN * NCHUNK);

    // ---- stage A tile (128 rows, 32KB) + B chunk 0 ----
    {
        const ushort* gA = fb + (size_t)rowbase * KD;
        #pragma unroll
        for (int i = 0; i < 4; i++) {
            int c = i * 512 + tid;                  // 16B chunk index
            bf16x8 v = *reinterpret_cast<const bf16x8*>(gA + c * 8);
            int dst = c ^ ((c >> 4) & 7);
            *reinterpret_cast<bf16x8*>(&As[dst * 8]) = v;
        }
        const ushort* gB = fb + (size_t)col0 * KD;
        #pragma unroll
        for (int i = 0; i < 2; i++) {
            int c = i * 512 + tid;
            bf16x8 v = *reinterpret_cast<const bf16x8*>(gB + c * 8);
            int dst = c ^ ((c >> 4) & 7);
            *reinterpret_cast<bf16x8*>(&Bs[0][dst * 8]) = v;
        }
    }
    __syncthreads();

    float pd[2][4];                   // [m][i] per-row exp-sum partials
    #pragma unroll
    for (int m = 0; m < 2; m++)
        #pragma unroll
        for (int i = 0; i < 4; i++) pd[m][i] = 0.f;

    int cur = 0;
    for (int c = 0; c < NCHUNK; c++) {
        // issue next-chunk global loads early (hide under MFMA+exp)
        bf16x8 pre0, pre1;
        if (c + 1 < NCHUNK) {
            const ushort* gB = fb + (size_t)(col0 + (c + 1) * BN) * KD;
            pre0 = *reinterpret_cast<const bf16x8*>(gB + (0 * 512 + tid) * 8);
            pre1 = *reinterpret_cast<const bf16x8*>(gB + (1 * 512 + tid) * 8);
        }

        f32x4 acc[2][2];
        #pragma unroll
        for (int m = 0; m < 2; m++)
            #pragma unroll
            for (int n = 0; n < 2; n++) acc[m][n] = f32x4{0.f, 0.f, 0.f, 0.f};

        const ushort* bbase = Bs[cur];
        #pragma unroll
        for (int ks = 0; ks < 4; ks++) {
            const int slot = ks * 4 + g4;
            bf16x8 av[2], bv[2];
            #pragma unroll
            for (int m = 0; m < 2; m++)
                av[m] = *lds_frag(As, wr * 32 + m * 16 + r16, slot);
            #pragma unroll
            for (int n = 0; n < 2; n++)
                bv[n] = *lds_frag(bbase, wc * 32 + n * 16 + r16, slot);
            #pragma unroll
            for (int m = 0; m < 2; m++)
                #pragma unroll
                for (int n = 0; n < 2; n++)
                    acc[m][n] = __builtin_amdgcn_mfma_f32_16x16x32_bf16(av[m], bv[n], acc[m][n], 0, 0, 0);
        }

        #pragma unroll
        for (int m = 0; m < 2; m++)
            #pragma unroll
            for (int n = 0; n < 2; n++)
                #pragma unroll
                for (int i = 0; i < 4; i++)
                    pd[m][i] += __builtin_amdgcn_exp2f(acc[m][n][i] * C_EXP);

        if (c + 1 < NCHUNK) {
            ushort* dstb = Bs[cur ^ 1];
            int ch;
            ch = 0 * 512 + tid; *reinterpret_cast<bf16x8*>(&dstb[(ch ^ ((ch >> 4) & 7)) * 8]) = pre0;
            ch = 1 * 512 + tid; *reinterpret_cast<bf16x8*>(&dstb[(ch ^ ((ch >> 4) & 7)) * 8]) = pre1;
        }
        __syncthreads();
        cur ^= 1;
    }

    // reduce across the 16 lanes sharing the same rows, write partials
    #pragma unroll
    for (int off = 1; off < 16; off <<= 1)
        #pragma unroll
        for (int m = 0; m < 2; m++)
            #pragma unroll
            for (int i = 0; i < 4; i++)
                pd[m][i] += __shfl_xor(pd[m][i], off);

    if (r16 == 0) {
        const int part = blockIdx.x * 2 + wc;   // 0..15
        #pragma unroll
        for (int m = 0; m < 2; m++)
            #pragma unroll
            for (int i = 0; i < 4; i++) {
                int r = rowbase + wr * 32 + m * 16 + g4 * 4 + i;
                denom_part[(size_t)r * NPART + part] = pd[m][i];
            }
    }
}

// ---------------- Kernel C: per-row loss ------------------------------------
__global__ void rowloss_kernel(const ushort* __restrict__ fb,
                               const int* __restrict__ labels,
                               const float* __restrict__ denom_part,
                               const float* __restrict__ sq,
                               const float* __restrict__ g,
                               const float* __restrict__ cntf,
                               float* __restrict__ rowloss,
                               int N) {
    int r    = (blockIdx.x * blockDim.x + threadIdx.x) >> 6;
    int lane = threadIdx.x & 63;
    if (r >= N) return;
    int lab = labels[r];
    unsigned int pk = *reinterpret_cast<const unsigned int*>(fb + (size_t)r * KD + lane * 2);
    float f0 = bf2f((ushort)(pk & 0xffff));
    float f1 = bf2f((ushort)(pk >> 16));
    const float2 gv = *reinterpret_cast<const float2*>(g + lab * 128 + lane * 2);
    float p = f0 * gv.x + f1 * gv.y;
    #pragma unroll
    for (int off = 1; off < 64; off <<= 1) p += __shfl_xor(p, off);

    float dsum = (lane < NPART) ? denom_part[(size_t)r * NPART + lane] : 0.f;
    #pragma unroll
    for (int off = 1; off < NPART; off <<= 1) dsum += __shfl_xor(dsum, off);

    if (lane == 0) {
        float sqr    = sq[r];
        float possum = (p - sqr) * TEMP_INV;
        float cnt    = cntf[lab] - 1.0f;
        float dn     = dsum - __builtin_amdgcn_exp2f(sqr * C_EXP);
        rowloss[r]   = -(possum - cnt * logf(dn + EPS)) / (cnt + EPS);
    }
}

// ---------------- Kernel D: mean (deterministic single-block reduce) --------
__global__ void reduce_kernel(const float* __restrict__ rowloss,
                              float* __restrict__ out, int N) {
    __shared__ float sdata[16];
    float s = 0.f;
    for (int r = threadIdx.x; r < N; r += blockDim.x) s += rowloss[r];
    #pragma unroll
    for (int off = 1; off < 64; off <<= 1) s += __shfl_xor(s, off);
    int wv = threadIdx.x >> 6;
    if ((threadIdx.x & 63) == 0) sdata[wv] = s;
    __syncthreads();
    if (threadIdx.x == 0) {
        float t = 0.f;
        int nw = (int)(blockDim.x >> 6);
        for (int i = 0; i < nw; i++) t += sdata[i];
        out[0] = t / (float)N;
    }
}

extern "C" void kernel_launch(void* const* d_in, const int* in_sizes, int n_in,
                              void* d_out, int out_size, void* d_ws, size_t ws_size,
                              hipStream_t stream) {
    const float* feat = (const float*)d_in[0];
    const int* labels = (const int*)d_in[1];
    const int N = in_sizes[1];

    char* ws = (char*)d_ws;
    size_t off = 0;
    ushort* fb        = (ushort*)(ws + off); off += (size_t)N * KD * sizeof(ushort);
    float* sq         = (float*)(ws + off);  off += (size_t)N * sizeof(float);
    float* g_part     = (float*)(ws + off);  off += (size_t)CS_BLOCKS * NUM_CLASSES * KD * sizeof(float);
    float* cnt_part   = (float*)(ws + off);  off += (size_t)CS_BLOCKS * NUM_CLASSES * sizeof(float);
    float* g          = (float*)(ws + off);  off += (size_t)NUM_CLASSES * KD * sizeof(float);
    float* cntf       = (float*)(ws + off);  off += (size_t)NUM_CLASSES * sizeof(float);
    float* denom_part = (float*)(ws + off);  off += (size_t)N * NPART * sizeof(float);
    float* rowloss    = (float*)(ws + off);

    normalize_kernel<<<(N + 3) / 4, 256, 0, stream>>>(feat, fb, sq, N);
    classsum_kernel<<<CS_BLOCKS, 256, 0, stream>>>(fb, labels, g_part, cnt_part, N);
    classreduce_kernel<<<NUM_CLASSES, 128, 0, stream>>>(g_part, cnt_part, g, cntf);

    dim3 grid(N / (BN * NCHUNK), N / BM);             // (8, 64) = 512 blocks
    supcon_denom<<<grid, 512, 0, stream>>>(fb, denom_part, N);

    rowloss_kernel<<<(N + 3) / 4, 256, 0, stream>>>(fb, labels, denom_part, sq, g, cntf, rowloss, N);
    reduce_kernel<<<1, 1024, 0, stream>>>(rowloss, (float*)d_out, N);
}